// Round 1
// baseline (896.608 us; speedup 1.0000x reference)
//
#include <hip/hip_runtime.h>
#include <hip/hip_bf16.h>

// HardMemory: x[32,512,64,64] f32, memory[1024,512] f32.
// sim = cos(x_pixel, mem_row); out[b,c,n] = memory[argmax][c] * (max>0.8)
// Pipeline: (1) normalize memory -> bf16, (2) MFMA GEMM + fused max/argmax,
// (3) masked gather/scatter epilogue.

typedef __attribute__((ext_vector_type(8))) short short8;   // 8 bf16 (4 VGPRs)
typedef __attribute__((ext_vector_type(4))) float f32x4;
typedef __attribute__((ext_vector_type(4))) int   i32x4;

#define THRESH 0.8f
#define EPSN   1e-12f

__device__ __forceinline__ short f2bf(float f) {
    union { float f; unsigned u; } v; v.f = f;
    unsigned r = v.u + 0x7fffu + ((v.u >> 16) & 1u);   // RNE
    return (short)(r >> 16);
}
__device__ __forceinline__ float bf2f(short h) {
    union { unsigned u; float f; } v;
    v.u = ((unsigned)(unsigned short)h) << 16;
    return v.f;
}

// ---------------- kernel 1: normalize memory rows -> bf16 ----------------
__global__ __launch_bounds__(256) void norm_mem_kernel(
        const float* __restrict__ mem, short* __restrict__ mem_bf) {
    const int row = blockIdx.x;          // 1024
    const int t   = threadIdx.x;         // 256
    const float* r = mem + (size_t)row * 512;
    float v0 = r[t], v1 = r[t + 256];
    float ss = v0 * v0 + v1 * v1;
    #pragma unroll
    for (int off = 32; off; off >>= 1) ss += __shfl_down(ss, off, 64);
    __shared__ float part[4];
    __shared__ float rinv_s;
    if ((t & 63) == 0) part[t >> 6] = ss;
    __syncthreads();
    if (t == 0) {
        float s = part[0] + part[1] + part[2] + part[3];
        rinv_s = 1.0f / fmaxf(sqrtf(s), EPSN);
    }
    __syncthreads();
    float rinv = rinv_s;
    mem_bf[(size_t)row * 512 + t]       = f2bf(v0 * rinv);
    mem_bf[(size_t)row * 512 + t + 256] = f2bf(v1 * rinv);
}

// ---------------- kernel 2: GEMM + fused row max/argmax ----------------
// Block: 64 pixels (one b, n0..n0+63) x all 1024 memories (16 chunks of 64).
// 4 waves in 2x2: wave tile 32 pixels x 32 mems via 4 mfma_f32_16x16x32_bf16.
// A (x-tile) staged in LDS, pre-fragmented: xs[oct][p] = 8 contiguous c's.
// B fragments loaded directly from L2-resident mem_bf (1 MiB).
__global__ __launch_bounds__(256, 2) void simmax_kernel(
        const float* __restrict__ x, const short* __restrict__ memn,
        int* __restrict__ selv) {
    __shared__ short xs[64 * 512];       // exactly 64 KiB; re-used for red arrays

    const int t    = threadIdx.x;
    const int b    = blockIdx.y;         // 32
    const int n0   = blockIdx.x * 64;    // 64 tiles of 64 pixels
    const int p    = t & 63;
    const int oct0 = t >> 6;

    // ---- stage X tile: x[b, c, n0+p] -> xs[(c/8)*64 + p][c%8] as bf16 ----
    const float* xb = x + ((size_t)b * 512) * 4096 + n0 + p;
    for (int oct = oct0; oct < 64; oct += 4) {
        short8 pk;
        #pragma unroll
        for (int i = 0; i < 8; ++i) {
            float v = xb[(size_t)(oct * 8 + i) * 4096];
            pk[i] = f2bf(v);
        }
        *(short8*)&xs[(oct * 64 + p) * 8] = pk;
    }
    __syncthreads();

    // ---- per-pixel ||x|| from staged tile (wave 0) ----
    float xnorm_reg = 1.0f;
    if (t < 64) {
        float s = 0.f;
        for (int oct = 0; oct < 64; ++oct) {
            short8 v = *(const short8*)&xs[(oct * 64 + t) * 8];
            #pragma unroll
            for (int i = 0; i < 8; ++i) { float f = bf2f(v[i]); s += f * f; }
        }
        xnorm_reg = fmaxf(sqrtf(s), EPSN);
    }

    const int w    = t >> 6;             // wave 0..3
    const int lane = t & 63;
    const int quad = lane >> 4;
    const int l15  = lane & 15;
    const int wp   = w >> 1;             // wave row (pixels)
    const int wm   = w & 1;              // wave col (mems)
    const int pa0  = wp * 32 + l15;      // A-frag pixel row (jm=0)

    float runv[2][4];
    int   runi[2][4];
    #pragma unroll
    for (int jm = 0; jm < 2; ++jm)
        #pragma unroll
        for (int r = 0; r < 4; ++r) { runv[jm][r] = -1e30f; runi[jm][r] = 0; }

    for (int mc = 0; mc < 16; ++mc) {
        f32x4 acc00 = {0.f, 0.f, 0.f, 0.f};
        f32x4 acc01 = acc00, acc10 = acc00, acc11 = acc00;
        const short* bbase =
            memn + (size_t)(mc * 64 + wm * 32 + l15) * 512 + quad * 8;
        #pragma unroll
        for (int kk = 0; kk < 512; kk += 32) {
            const int oct = (kk >> 3) + quad;
            short8 a0 = *(const short8*)&xs[(oct * 64 + pa0) * 8];
            short8 a1 = *(const short8*)&xs[(oct * 64 + pa0 + 16) * 8];
            short8 b0 = *(const short8*)(bbase + kk);
            short8 b1 = *(const short8*)(bbase + 16 * 512 + kk);
            acc00 = __builtin_amdgcn_mfma_f32_16x16x32_bf16(a0, b0, acc00, 0, 0, 0);
            acc01 = __builtin_amdgcn_mfma_f32_16x16x32_bf16(a0, b1, acc01, 0, 0, 0);
            acc10 = __builtin_amdgcn_mfma_f32_16x16x32_bf16(a1, b0, acc10, 0, 0, 0);
            acc11 = __builtin_amdgcn_mfma_f32_16x16x32_bf16(a1, b1, acc11, 0, 0, 0);
        }
        const int colbase = mc * 64 + wm * 32;
        #pragma unroll
        for (int r = 0; r < 4; ++r) {
            float v; int c;
            v = acc00[r]; c = colbase + l15;
            if (v > runv[0][r]) { runv[0][r] = v; runi[0][r] = c; }
            v = acc01[r]; c = colbase + 16 + l15;
            if (v > runv[0][r]) { runv[0][r] = v; runi[0][r] = c; }
            v = acc10[r]; c = colbase + l15;
            if (v > runv[1][r]) { runv[1][r] = v; runi[1][r] = c; }
            v = acc11[r]; c = colbase + 16 + l15;
            if (v > runv[1][r]) { runv[1][r] = v; runi[1][r] = c; }
        }
    }

    // ---- cross-lane max/argmax (16 lanes per quad hold the 16 cols) ----
    float myv[2][4]; int myi[2][4];
    #pragma unroll
    for (int jm = 0; jm < 2; ++jm)
        #pragma unroll
        for (int r = 0; r < 4; ++r) {
            float v = runv[jm][r]; int i = runi[jm][r];
            #pragma unroll
            for (int off = 1; off < 16; off <<= 1) {
                float ov = __shfl_xor(v, off, 64);
                int   oi = __shfl_xor(i, off, 64);
                if (ov > v || (ov == v && oi < i)) { v = ov; i = oi; }
            }
            myv[jm][r] = v; myi[jm][r] = i;
        }

    __syncthreads();   // all xs reads done; re-use xs as reduction scratch
    float* redv = (float*)xs;            // [2][64]
    int*   redi = (int*)xs + 128;        // [2][64]
    if (l15 == 0) {
        #pragma unroll
        for (int jm = 0; jm < 2; ++jm)
            #pragma unroll
            for (int r = 0; r < 4; ++r) {
                int row_local = wp * 32 + jm * 16 + quad * 4 + r;
                redv[wm * 64 + row_local] = myv[jm][r];
                redi[wm * 64 + row_local] = myi[jm][r];
            }
    }
    __syncthreads();
    if (t < 64) {
        float v0 = redv[t], v1 = redv[64 + t];
        int   i0 = redi[t], i1 = redi[64 + t];
        float v = v0; int i = i0;
        if (v1 > v || (v1 == v && i1 < i)) { v = v1; i = i1; }
        float maxval = v / xnorm_reg;
        selv[(size_t)b * 4096 + n0 + t] = (maxval > THRESH) ? i : -1;
    }
}

// ---------------- kernel 3: masked gather -> transposed output ----------------
// out[b, c, n] = sel[b,n] >= 0 ? memory[sel][c] : 0
__global__ __launch_bounds__(256) void scatter_kernel(
        const float* __restrict__ mem, const int* __restrict__ selv,
        float* __restrict__ out) {
    const int t  = threadIdx.x;          // 256
    const int nt = blockIdx.x;           // 4   (1024 n per block, 4 per thread)
    const int b  = blockIdx.y;           // 32
    const int cs = blockIdx.z;           // 8   (64 c per block)
    const int n  = nt * 1024 + t * 4;
    i32x4 sel = *(const i32x4*)&selv[(size_t)b * 4096 + n];
    float* ob = out + ((size_t)b * 512 + cs * 64) * 4096 + n;
    const int c0 = cs * 64;
    for (int c = 0; c < 64; ++c) {
        f32x4 v;
        v.x = (sel.x >= 0) ? mem[(size_t)sel.x * 512 + c0 + c] : 0.f;
        v.y = (sel.y >= 0) ? mem[(size_t)sel.y * 512 + c0 + c] : 0.f;
        v.z = (sel.z >= 0) ? mem[(size_t)sel.z * 512 + c0 + c] : 0.f;
        v.w = (sel.w >= 0) ? mem[(size_t)sel.w * 512 + c0 + c] : 0.f;
        *(f32x4*)&ob[(size_t)c * 4096] = v;
    }
}

extern "C" void kernel_launch(void* const* d_in, const int* in_sizes, int n_in,
                              void* d_out, int out_size, void* d_ws, size_t ws_size,
                              hipStream_t stream) {
    const float* x   = (const float*)d_in[0];   // [32,512,64,64]
    const float* mem = (const float*)d_in[1];   // [1024,512]
    short* mem_bf = (short*)d_ws;                       // 1 MiB bf16 normalized
    int*   selv   = (int*)((char*)d_ws + (1 << 20));    // 512 KiB selections
    float* out    = (float*)d_out;

    norm_mem_kernel<<<dim3(1024), dim3(256), 0, stream>>>(mem, mem_bf);
    simmax_kernel<<<dim3(64, 32), dim3(256), 0, stream>>>(x, mem_bf, selv);
    scatter_kernel<<<dim3(4, 32, 8), dim3(256), 0, stream>>>(mem, selv, out);
}